// Round 1
// baseline (811.166 us; speedup 1.0000x reference)
//
#include <hip/hip_runtime.h>
#include <math.h>

#define NPTS   4096   // points per set (n == m)
#define NPROJ  2000   // projections
#define NB     256    // threads per block
#define NMERGE 8192   // n + m
#define NBINS  8192   // cdf levels c in [-4096, 4095] (c=+4096 clamped; needs all u < all v)

__global__ __launch_bounds__(NB) void swd_kernel(
    const float* __restrict__ Xs, const float* __restrict__ Xt,
    const float* __restrict__ Us, float* __restrict__ out)
{
    // 64 KB LDS total: keys holds u||v angles (sorted in place), hist holds
    // delta-weight per integer cdf level. keys is reused as scratch after merge.
    __shared__ float keys[NMERGE];
    __shared__ float hist[NBINS];

    const int tid = threadIdx.x;
    const int p = blockIdx.x;

    // projection matrix for this block (broadcast reads, L2-resident)
    const float u00 = Us[p*6+0], u01 = Us[p*6+1];
    const float u10 = Us[p*6+2], u11 = Us[p*6+3];
    const float u20 = Us[p*6+4], u21 = Us[p*6+5];

    const float pi_f    = 3.14159265358979323846f;
    const float inv2pi  = 0.15915494309189535f;

    // ---- angles: atan2 is scale-invariant so F.normalize can be skipped ----
    for (int i = tid; i < NPTS; i += NB) {
        float a0 = Xs[i*3+0], a1 = Xs[i*3+1], a2 = Xs[i*3+2];
        float px = a0*u00 + a1*u10 + a2*u20;
        float py = a0*u01 + a1*u11 + a2*u21;
        keys[i] = (atan2f(-py, -px) + pi_f) * inv2pi;

        float b0 = Xt[i*3+0], b1 = Xt[i*3+1], b2 = Xt[i*3+2];
        float qx = b0*u00 + b1*u10 + b2*u20;
        float qy = b0*u01 + b1*u11 + b2*u21;
        keys[NPTS + i] = (atan2f(-qy, -qx) + pi_f) * inv2pi;
    }
    for (int i = tid; i < NBINS; i += NB) hist[i] = 0.0f;
    __syncthreads();

    // ---- bitonic sort of both 4096-element halves simultaneously ----
    // 4096 compare-exchange pairs per step (2048 per array), 16 per thread.
    for (int k = 2; k <= NPTS; k <<= 1) {
        for (int j = k >> 1; j > 0; j >>= 1) {
            for (int t = tid; t < NMERGE/2; t += NB) {
                int arr = t >> 11;            // which array (0=u, 1=v)
                int pr  = t & 2047;           // pair index within array
                int i1 = ((pr & ~(j-1)) << 1) | (pr & (j-1));
                int i2 = i1 | j;
                int b = arr << 12;
                float a = keys[b + i1], c = keys[b + i2];
                bool asc = ((i1 & k) == 0);
                if ((a > c) == asc) { keys[b + i1] = c; keys[b + i2] = a; }
            }
            __syncthreads();
        }
    }

    // ---- merge-path merge; scatter delta into level histogram ----
    // Level after taking merged element i is c = (#u taken) - (#v taken);
    // cdf_diff value is exactly c/4096 (dyadic, exact in fp32).
    {
        const int per = NMERGE / NB;          // 32 merged outputs per thread
        int d = tid * per;
        int lo = d > NPTS ? d - NPTS : 0;
        int hi = d < NPTS ? d : NPTS;
        while (lo < hi) {                     // u[mid] vs v[d-1-mid], ties: u first
            int mid = (lo + hi) >> 1;
            if (keys[mid] <= keys[NPTS + (d - 1 - mid)]) lo = mid + 1; else hi = mid;
        }
        int i = lo, j = d - lo;
        const float FMAXV = 3.402823466e+38f;
        float cu = (i < NPTS) ? keys[i] : FMAXV;
        float cv = (j < NPTS) ? keys[NPTS + j] : FMAXV;
        for (int s = 0; s < per; ++s) {
            float cur;
            if (cu <= cv) { cur = cu; ++i; cu = (i < NPTS) ? keys[i] : FMAXV; }
            else          { cur = cv; ++j; cv = (j < NPTS) ? keys[NPTS + j] : FMAXV; }
            float nxt = fminf(cu, cv);
            if (nxt == FMAXV) nxt = 1.0f;     // vals_pad appends 1.0 at global end
            int bin = (i - j) + 4096;
            if (bin > NBINS - 1) bin = NBINS - 1;
            atomicAdd(&hist[bin], nxt - cur);
        }
    }
    __syncthreads();

    // ---- level median: first level c* where prefix weight >= 0.5 ----
    {
        float s = 0.0f;
        int base = tid * (NBINS / NB);
        #pragma unroll
        for (int b = 0; b < NBINS / NB; ++b) s += hist[base + b];
        keys[tid] = s;                        // keys reused as scratch (post-barrier)
    }
    __syncthreads();
    if (tid == 0) {
        float run = 0.0f; int cstar = NBINS - 1; bool found = false;
        for (int t = 0; t < NB && !found; ++t) {
            float cs = keys[t];
            if (run + cs >= 0.5f) {
                int bb = t * (NBINS / NB);
                for (int b = 0; b < NBINS / NB; ++b) {
                    run += hist[bb + b];
                    if (run >= 0.5f) { cstar = bb + b; found = true; break; }
                }
            } else {
                run += cs;
            }
        }
        keys[0] = (float)cstar;
    }
    __syncthreads();

    // ---- w1 = (1/4096) * sum_c hist[c] * |c - c*| ; mean over projections ----
    const int cstar = (int)keys[0];
    float partial = 0.0f;
    for (int b = tid; b < NBINS; b += NB) {
        int dc = b - cstar;
        partial += hist[b] * (float)(dc < 0 ? -dc : dc);
    }
    #pragma unroll
    for (int off = 32; off > 0; off >>= 1) partial += __shfl_down(partial, off, 64);
    __syncthreads();
    if ((tid & 63) == 0) keys[1 + (tid >> 6)] = partial;
    __syncthreads();
    if (tid == 0) {
        float w1 = (keys[1] + keys[2] + keys[3] + keys[4]) * (1.0f / 4096.0f);
        atomicAdd(out, w1 * (1.0f / (float)NPROJ));
    }
}

extern "C" void kernel_launch(void* const* d_in, const int* in_sizes, int n_in,
                              void* d_out, int out_size, void* d_ws, size_t ws_size,
                              hipStream_t stream) {
    const float* Xs = (const float*)d_in[0];
    const float* Xt = (const float*)d_in[1];
    const float* Us = (const float*)d_in[2];
    float* out = (float*)d_out;

    // d_out is poisoned before every launch; zero it (async, capture-safe).
    hipMemsetAsync(out, 0, sizeof(float), stream);
    swd_kernel<<<NPROJ, NB, 0, stream>>>(Xs, Xt, Us, out);
}

// Round 2
// 313.288 us; speedup vs baseline: 2.5892x; 2.5892x over previous
//
#include <hip/hip_runtime.h>
#include <math.h>

#define NPTS   4096   // points per set (n == m)
#define NPROJ  2000   // projections
#define NB     256    // threads per block
#define NMERGE 8192   // n + m
#define NBINS  8192   // cdf levels c in [-4096, 4095]
#define VPT    32     // values per thread (in registers)

// XOR-rotate swizzle: element-within-chunk rotated by chunk index (chunk = i>>5).
// Kills the 64-way column bank conflicts of keys[tid*32 + e] stores.
__device__ __forceinline__ int sw(int i) {
    return (i & ~31) | ((i + (i >> 5)) & 31);
}

// Bitonic local merge of 32 in-register elements, steps j=16..1, uniform direction.
__device__ __forceinline__ void local_merge(float v[VPT], bool asc) {
    #pragma unroll
    for (int j = 16; j >= 1; j >>= 1) {
        #pragma unroll
        for (int e = 0; e < VPT; ++e) {
            if ((e & j) == 0) {
                float a = v[e], b = v[e | j];
                float mn = fminf(a, b), mx = fmaxf(a, b);
                v[e]     = asc ? mn : mx;
                v[e | j] = asc ? mx : mn;
            }
        }
    }
}

__global__ __launch_bounds__(NB, 2) void swd_kernel(
    const float* __restrict__ Xs, const float* __restrict__ Xt,
    const float* __restrict__ Us, float* __restrict__ out)
{
    __shared__ float keys[NMERGE];   // sorted u || sorted v (swizzled addressing)
    __shared__ float hist[NBINS];    // delta-weight per integer cdf level
    __shared__ int   s_cstar;

    const int tid  = threadIdx.x;
    const int arr  = tid >> 7;       // 0 = Xs chunk-owner, 1 = Xt
    const int c    = tid & 127;      // chunk index within this array (32 elems/chunk)
    const int lane = tid & 63;
    const int wid  = tid >> 6;
    const int p    = blockIdx.x;

    const float u00 = Us[p*6+0], u01 = Us[p*6+1];
    const float u10 = Us[p*6+2], u11 = Us[p*6+3];
    const float u20 = Us[p*6+4], u21 = Us[p*6+5];

    const float pi_f   = 3.14159265358979323846f;
    const float inv2pi = 0.15915494309189535f;

    const float* __restrict__ X = arr ? Xt : Xs;

    // ---- angles into registers (atan2 is scale-invariant; F.normalize skipped) ----
    float v[VPT];
    {
        const float4* X4 = (const float4*)(X + c * (VPT * 3));  // 96 floats, 16B aligned
        #pragma unroll
        for (int t = 0; t < 8; ++t) {
            float4 q0 = X4[t*3+0], q1 = X4[t*3+1], q2 = X4[t*3+2];
            #define ANG(x,y,z) ((atan2f(-((x)*u01+(y)*u11+(z)*u21), \
                                        -((x)*u00+(y)*u10+(z)*u20)) + pi_f) * inv2pi)
            v[t*4+0] = ANG(q0.x, q0.y, q0.z);
            v[t*4+1] = ANG(q0.w, q1.x, q1.y);
            v[t*4+2] = ANG(q1.z, q1.w, q2.x);
            v[t*4+3] = ANG(q2.y, q2.z, q2.w);
            #undef ANG
        }
    }

    for (int i = tid; i < NBINS; i += NB) hist[i] = 0.0f;
    if (tid == 0) s_cstar = NBINS - 1;

    // ---- phases k=2..16: intra-thread, compile-time directions ----
    #pragma unroll
    for (int k = 2; k <= 16; k <<= 1) {
        #pragma unroll
        for (int j = k >> 1; j >= 1; j >>= 1) {
            #pragma unroll
            for (int e = 0; e < VPT; ++e) {
                if ((e & j) == 0) {
                    bool asc = ((e & k) == 0);
                    float a = v[e], b = v[e | j];
                    float mn = fminf(a, b), mx = fmaxf(a, b);
                    v[e]     = asc ? mn : mx;
                    v[e | j] = asc ? mx : mn;
                }
            }
        }
    }

    // ---- phase k=32: fully local, direction uniform per thread ----
    local_merge(v, (c & 1) == 0);

    // ---- phases k=64..2048: within-wave shfl_xor exchanges + local merge ----
    #pragma unroll
    for (int k = 64; k <= 2048; k <<= 1) {
        bool asc = ((c & (k >> 5)) == 0);
        #pragma unroll
        for (int d = k >> 6; d >= 1; d >>= 1) {     // j = k/2 .. 32
            bool keepmin = (((c & d) == 0) == asc);
            #pragma unroll
            for (int e = 0; e < VPT; ++e) {
                float o = __shfl_xor(v[e], d, 64);
                v[e] = keepmin ? fminf(v[e], o) : fmaxf(v[e], o);
            }
        }
        local_merge(v, asc);
    }

    // ---- phase k=4096 (full ascending merge) ----
    // j=2048 crosses waves (chunk xor 64): one LDS round-trip.
    #pragma unroll
    for (int e = 0; e < VPT; ++e) keys[sw(tid * VPT + e)] = v[e];
    __syncthreads();
    {
        const int pbase = (tid ^ 64) * VPT;
        const bool keepmin = (c & 64) == 0;          // asc = true
        #pragma unroll
        for (int e = 0; e < VPT; ++e) {
            float o = keys[sw(pbase + e)];
            v[e] = keepmin ? fminf(v[e], o) : fmaxf(v[e], o);
        }
    }
    __syncthreads();   // all partner reads complete before keys is overwritten
    #pragma unroll
    for (int d = 32; d >= 1; d >>= 1) {              // j = 1024 .. 32
        bool keepmin = ((c & d) == 0);
        #pragma unroll
        for (int e = 0; e < VPT; ++e) {
            float o = __shfl_xor(v[e], d, 64);
            v[e] = keepmin ? fminf(v[e], o) : fmaxf(v[e], o);
        }
    }
    local_merge(v, true);

    // store sorted arrays for the merge
    #pragma unroll
    for (int e = 0; e < VPT; ++e) keys[sw(tid * VPT + e)] = v[e];
    __syncthreads();

    // ---- merge-path merge; scatter delta into level histogram ----
    // Level after merged element = (#u taken) - (#v taken); cdf value = c/4096 exact.
    {
        const int per = NMERGE / NB;          // 32 merged outputs per thread
        const int d0 = tid * per;
        int lo = d0 > NPTS ? d0 - NPTS : 0;
        int hi = d0 < NPTS ? d0 : NPTS;
        while (lo < hi) {                     // ties: u first (stable argsort)
            int mid = (lo + hi) >> 1;
            if (keys[sw(mid)] <= keys[sw(NPTS + (d0 - 1 - mid))]) lo = mid + 1; else hi = mid;
        }
        int i = lo, j = d0 - lo;
        const float FMAXV = 3.402823466e+38f;
        float cu = (i < NPTS) ? keys[sw(i)] : FMAXV;
        float cv = (j < NPTS) ? keys[sw(NPTS + j)] : FMAXV;
        for (int s = 0; s < per; ++s) {
            float cur;
            if (cu <= cv) { cur = cu; ++i; cu = (i < NPTS) ? keys[sw(i)] : FMAXV; }
            else          { cur = cv; ++j; cv = (j < NPTS) ? keys[sw(NPTS + j)] : FMAXV; }
            float nxt = fminf(cu, cv);
            if (nxt == FMAXV) nxt = 1.0f;     // vals_pad appends 1.0
            int bin = (i - j) + 4096;
            if (bin > NBINS - 1) bin = NBINS - 1;
            atomicAdd(&hist[bin], nxt - cur);
        }
    }
    __syncthreads();

    // ---- level median: parallel prefix over 256 column sums ----
    const int cbase = tid * (NBINS / NB);     // 32 bins per thread
    float colsum = 0.0f;
    #pragma unroll
    for (int b = 0; b < 32; ++b) colsum += hist[cbase + ((b + tid) & 31)];  // rotated: no bank conflict

    float ps = colsum;
    #pragma unroll
    for (int o = 1; o < 64; o <<= 1) {
        float t2 = __shfl_up(ps, o, 64);
        if (lane >= o) ps += t2;
    }
    if (lane == 63) keys[wid] = ps;           // keys free after merge barrier
    __syncthreads();
    float wbase = 0.0f;
    #pragma unroll
    for (int w = 0; w < 4; ++w) wbase += (w < wid) ? keys[w] : 0.0f;
    float incl = wbase + ps;
    float excl = incl - colsum;
    if (incl >= 0.5f && excl < 0.5f + 1e-6f) {   // slack: fp-rounding can't drop the crossing
        float run = excl;
        int found = cbase + 31;
        #pragma unroll
        for (int b = 0; b < 32; ++b) {
            run += hist[cbase + b];
            if (run >= 0.5f) { found = cbase + b; break; }
        }
        atomicMin(&s_cstar, found);
    }
    __syncthreads();
    const int cstar = s_cstar;

    // ---- w1 = (1/4096) * sum_c hist[c] * |c - c*| ----
    float part = 0.0f;
    for (int b = tid; b < NBINS; b += NB) {
        int dc = b - cstar;
        part += hist[b] * (float)(dc < 0 ? -dc : dc);
    }
    #pragma unroll
    for (int o = 32; o >= 1; o >>= 1) part += __shfl_down(part, o, 64);
    __syncthreads();
    if (lane == 0) keys[wid] = part;
    __syncthreads();
    if (tid == 0) {
        float w1 = (keys[0] + keys[1] + keys[2] + keys[3]) * (1.0f / 4096.0f);
        atomicAdd(out, w1 * (1.0f / (float)NPROJ));
    }
}

extern "C" void kernel_launch(void* const* d_in, const int* in_sizes, int n_in,
                              void* d_out, int out_size, void* d_ws, size_t ws_size,
                              hipStream_t stream) {
    const float* Xs = (const float*)d_in[0];
    const float* Xt = (const float*)d_in[1];
    const float* Us = (const float*)d_in[2];
    float* out = (float*)d_out;

    hipMemsetAsync(out, 0, sizeof(float), stream);
    swd_kernel<<<NPROJ, NB, 0, stream>>>(Xs, Xt, Us, out);
}

// Round 3
// 238.946 us; speedup vs baseline: 3.3948x; 1.3111x over previous
//
#include <hip/hip_runtime.h>
#include <math.h>

#define NPTS   4096   // points per set (n == m)
#define NPROJ  2000   // projections
#define NB     256    // threads per block
#define NMERGE 8192   // n + m
#define VPT    32     // values per thread (in registers)

// XOR-rotate swizzle: element-within-chunk rotated by chunk index (chunk = i>>5).
__device__ __forceinline__ int sw(int i) {
    return (i & ~31) | ((i + (i >> 5)) & 31);
}

// Bitonic local merge of 32 in-register elements, steps j=16..1, uniform direction.
__device__ __forceinline__ void local_merge(float v[VPT], bool asc) {
    #pragma unroll
    for (int j = 16; j >= 1; j >>= 1) {
        #pragma unroll
        for (int e = 0; e < VPT; ++e) {
            if ((e & j) == 0) {
                float a = v[e], b = v[e | j];
                float mn = fminf(a, b), mx = fmaxf(a, b);
                v[e]     = asc ? mn : mx;
                v[e | j] = asc ? mx : mn;
            }
        }
    }
}

__global__ __launch_bounds__(NB, 4) void swd_kernel(
    const float* __restrict__ Xs, const float* __restrict__ Xt,
    const float* __restrict__ Us, float* __restrict__ out)
{
    __shared__ float keys[NMERGE];   // sorted u || sorted v (swizzled addressing); ~32 KB
    __shared__ float red[15 * 4];    // per-iteration wave partials (one barrier/iter)

    const int tid  = threadIdx.x;
    const int arr  = tid >> 7;       // 0 = Xs chunk-owner, 1 = Xt
    const int c    = tid & 127;      // chunk index within this array (32 elems/chunk)
    const int lane = tid & 63;
    const int wid  = tid >> 6;
    const int p    = blockIdx.x;

    const float u00 = Us[p*6+0], u01 = Us[p*6+1];
    const float u10 = Us[p*6+2], u11 = Us[p*6+3];
    const float u20 = Us[p*6+4], u21 = Us[p*6+5];

    const float pi_f   = 3.14159265358979323846f;
    const float inv2pi = 0.15915494309189535f;

    const float* __restrict__ X = arr ? Xt : Xs;

    // ---- angles into registers (atan2 is scale-invariant; F.normalize skipped) ----
    float v[VPT];
    {
        const float4* X4 = (const float4*)(X + c * (VPT * 3));  // 96 floats, 16B aligned
        #pragma unroll
        for (int t = 0; t < 8; ++t) {
            float4 q0 = X4[t*3+0], q1 = X4[t*3+1], q2 = X4[t*3+2];
            #define ANG(x,y,z) ((atan2f(-((x)*u01+(y)*u11+(z)*u21), \
                                        -((x)*u00+(y)*u10+(z)*u20)) + pi_f) * inv2pi)
            v[t*4+0] = ANG(q0.x, q0.y, q0.z);
            v[t*4+1] = ANG(q0.w, q1.x, q1.y);
            v[t*4+2] = ANG(q1.z, q1.w, q2.x);
            v[t*4+3] = ANG(q2.y, q2.z, q2.w);
            #undef ANG
        }
    }

    // ---- phases k=2..16: intra-thread, compile-time directions ----
    #pragma unroll
    for (int k = 2; k <= 16; k <<= 1) {
        #pragma unroll
        for (int j = k >> 1; j >= 1; j >>= 1) {
            #pragma unroll
            for (int e = 0; e < VPT; ++e) {
                if ((e & j) == 0) {
                    bool asc = ((e & k) == 0);
                    float a = v[e], b = v[e | j];
                    float mn = fminf(a, b), mx = fmaxf(a, b);
                    v[e]     = asc ? mn : mx;
                    v[e | j] = asc ? mx : mn;
                }
            }
        }
    }

    // ---- phase k=32: fully local, direction uniform per thread ----
    local_merge(v, (c & 1) == 0);

    // ---- phases k=64..2048: within-wave shfl_xor exchanges + local merge ----
    #pragma unroll
    for (int k = 64; k <= 2048; k <<= 1) {
        bool asc = ((c & (k >> 5)) == 0);
        #pragma unroll
        for (int d = k >> 6; d >= 1; d >>= 1) {     // j = k/2 .. 32
            bool keepmin = (((c & d) == 0) == asc);
            #pragma unroll
            for (int e = 0; e < VPT; ++e) {
                float o = __shfl_xor(v[e], d, 64);
                v[e] = keepmin ? fminf(v[e], o) : fmaxf(v[e], o);
            }
        }
        local_merge(v, asc);
    }

    // ---- phase k=4096 (full ascending merge) ----
    // j=2048 crosses waves (chunk xor 64): one LDS round-trip.
    #pragma unroll
    for (int e = 0; e < VPT; ++e) keys[sw(tid * VPT + e)] = v[e];
    __syncthreads();
    {
        const int pbase = (tid ^ 64) * VPT;
        const bool keepmin = (c & 64) == 0;          // asc = true
        #pragma unroll
        for (int e = 0; e < VPT; ++e) {
            float o = keys[sw(pbase + e)];
            v[e] = keepmin ? fminf(v[e], o) : fmaxf(v[e], o);
        }
    }
    __syncthreads();   // all partner reads complete before keys is overwritten
    #pragma unroll
    for (int d = 32; d >= 1; d >>= 1) {              // j = 1024 .. 32
        bool keepmin = ((c & d) == 0);
        #pragma unroll
        for (int e = 0; e < VPT; ++e) {
            float o = __shfl_xor(v[e], d, 64);
            v[e] = keepmin ? fminf(v[e], o) : fmaxf(v[e], o);
        }
    }
    local_merge(v, true);

    // store sorted arrays for the merge
    #pragma unroll
    for (int e = 0; e < VPT; ++e) keys[sw(tid * VPT + e)] = v[e];
    __syncthreads();

    // ---- merge-path merge; keep (delta, c-offset) per element in registers ----
    // Level after merged element = (#u taken) - (#v taken); cdf value = c/4096 exact.
    // delta goes into v[s]; c stored as int8 offset from c_init, packed 4/VGPR.
    int c_init;
    unsigned int c8[8] = {0,0,0,0,0,0,0,0};
    {
        const int d0 = tid * VPT;
        int lo = d0 > NPTS ? d0 - NPTS : 0;
        int hi = d0 < NPTS ? d0 : NPTS;
        while (lo < hi) {                     // ties: u first (stable argsort)
            int mid = (lo + hi) >> 1;
            if (keys[sw(mid)] <= keys[sw(NPTS + (d0 - 1 - mid))]) lo = mid + 1; else hi = mid;
        }
        int i = lo, j = d0 - lo;
        c_init = i - j;
        const float FMAXV = 3.402823466e+38f;
        float cu = (i < NPTS) ? keys[sw(i)] : FMAXV;
        float cv = (j < NPTS) ? keys[sw(NPTS + j)] : FMAXV;
        #pragma unroll
        for (int s = 0; s < VPT; ++s) {
            float cur;
            if (cu <= cv) { cur = cu; ++i; cu = (i < NPTS) ? keys[sw(i)] : FMAXV; }
            else          { cur = cv; ++j; cv = (j < NPTS) ? keys[sw(NPTS + j)] : FMAXV; }
            float nxt = fminf(cu, cv);
            if (nxt == FMAXV) nxt = 1.0f;     // vals_pad appends 1.0
            v[s] = nxt - cur;                 // delta (>= 0)
            int off = (i - j) - c_init;       // in [-32, 32]
            c8[s >> 2] |= ((unsigned int)(off & 0xff)) << ((s & 3) * 8);
        }
    }

    // ---- level median c* via integer bisection (no histogram, no atomics) ----
    // c* = smallest c with W(<= c) >= 0.5, W = sum of deltas at levels <= c.
    int lo_c = -4097, hi_c = 4096;
    #pragma unroll 1
    for (int it = 0; it < 14; ++it) {
        const int mid = (lo_c + hi_c) >> 1;   // uniform across block
        const int thr = mid - c_init;
        float s_loc = 0.0f;
        #pragma unroll
        for (int s = 0; s < VPT; ++s) {
            int off = (int)(c8[s >> 2] << ((3 - (s & 3)) * 8)) >> 24;  // sign-extended byte
            s_loc += (off <= thr) ? v[s] : 0.0f;
        }
        #pragma unroll
        for (int o = 32; o >= 1; o >>= 1) s_loc += __shfl_down(s_loc, o, 64);
        if (lane == 0) red[it * 4 + wid] = s_loc;
        __syncthreads();
        float S = red[it*4+0] + red[it*4+1] + red[it*4+2] + red[it*4+3];
        if (S >= 0.5f) hi_c = mid; else lo_c = mid;
    }
    const int cstar = hi_c;

    // ---- w1 = (1/4096) * sum delta * |c - c*| (register pass + one reduction) ----
    float part = 0.0f;
    {
        const int thr = cstar - c_init;
        #pragma unroll
        for (int s = 0; s < VPT; ++s) {
            int off = (int)(c8[s >> 2] << ((3 - (s & 3)) * 8)) >> 24;
            part += v[s] * fabsf((float)(off - thr));
        }
    }
    #pragma unroll
    for (int o = 32; o >= 1; o >>= 1) part += __shfl_down(part, o, 64);
    if (lane == 0) red[56 + wid] = part;
    __syncthreads();
    if (tid == 0) {
        float w1 = (red[56] + red[57] + red[58] + red[59]) * (1.0f / 4096.0f);
        atomicAdd(out, w1 * (1.0f / (float)NPROJ));
    }
}

extern "C" void kernel_launch(void* const* d_in, const int* in_sizes, int n_in,
                              void* d_out, int out_size, void* d_ws, size_t ws_size,
                              hipStream_t stream) {
    const float* Xs = (const float*)d_in[0];
    const float* Xt = (const float*)d_in[1];
    const float* Us = (const float*)d_in[2];
    float* out = (float*)d_out;

    hipMemsetAsync(out, 0, sizeof(float), stream);
    swd_kernel<<<NPROJ, NB, 0, stream>>>(Xs, Xt, Us, out);
}